// Round 14
// baseline (663.326 us; speedup 1.0000x reference)
//
#include <hip/hip_runtime.h>
#include <math.h>

// Persistent Sinkhorn R14: 6 blocks/CU WITHOUT the launch_bounds hint.
//
// R13 post-mortem: gate FAILED again -- (256,5) hint made the compiler pick
// 48 VGPR (spill; WRITE 592MB). Same failure as R10's (256,6). The hint is
// the confound, not occupancy. Clean test: keep (256,4) (reliably VGPR=64,
// codegen identical to R12) and launch NBLK=24, grid=1536=256CUx6. At
// VGPR=64 the HW itself allows: VGPR->8 blk/CU, threads->8, LDS 26.1KB->6.
// Exact-capacity grid -> whole grid resident -> spin barrier safe.
//
// Gates: VGPR_Count ~64, WRITE_SIZE ~380-400MB. Pre-commit: clean gates +
// fused >= 250us -> occupancy refuted -> ROOFLINE.
//
// Carried (proven R3-R12): per-batch monotonic barrier (relaxed agent
// atomics + vmcnt(0) drain); fp16-pair coherent P; 1 barrier/iter;
// plain-sum col partials via exp reuse; conflict-free pbuf[4][64][17];
// dual-row+prefetch ILP; no-max-shift log2-domain lse; NT out/m;
// early zero-fill + degenerate exit; deterministic early-exit check (free).
//
// ws: bar@0 (4KB) | P16@1MB (2 x B*24*512*4B = 2x3MB) | mh@16MB (128MB).

#define BIGNEG (-1e30f)
#define LOG2E 1.44269504f
#define DVTHR 0.001953125f  // 2^-9 log2-units convergence threshold
typedef _Float16 h16;
struct alignas(16) h8 { h16 h[8]; };
typedef float f4 __attribute__((ext_vector_type(4)));  // NT-compatible vec4

#define NN 1024
#define MM 1024
#define NBLK 24            // blocks per batch (6 blocks/CU, LDS-limited)
#define WPB (NBLK * 4)     // waves per batch = 96

__device__ __forceinline__ float wave_sum64(float v) {
#pragma unroll
    for (int o = 32; o > 0; o >>= 1) v += __shfl_xor(v, o, 64);
    return v;
}
__device__ __forceinline__ float wave_max64(float v) {
#pragma unroll
    for (int o = 32; o > 0; o >>= 1) v = fmaxf(v, __shfl_xor(v, o, 64));
    return v;
}

__device__ __forceinline__ unsigned ld_cohu(const unsigned* p) {
    return __hip_atomic_load(p, __ATOMIC_RELAXED, __HIP_MEMORY_SCOPE_AGENT);
}
__device__ __forceinline__ void st_cohu(unsigned* p, unsigned v) {
    __hip_atomic_store(p, v, __ATOMIC_RELAXED, __HIP_MEMORY_SCOPE_AGENT);
}

__global__ void zero_bar(unsigned* bar, int n) {
    const int i = blockIdx.x * blockDim.x + threadIdx.x;
    if (i < n) bar[i] = 0;
}

// Monotonic per-batch barrier (proven R3-R12). Relaxed atomics; each wave
// drains its own sc1 stores to the coherence point before arriving.
#define BATCH_BAR()                                                            \
    do {                                                                       \
        asm volatile("s_waitcnt vmcnt(0)" ::: "memory");                       \
        __syncthreads();                                                       \
        ++phase;                                                               \
        if (threadIdx.x == 0) {                                                \
            __hip_atomic_fetch_add(ctr, 1u, __ATOMIC_RELAXED,                  \
                                   __HIP_MEMORY_SCOPE_AGENT);                  \
            while (__hip_atomic_load(ctr, __ATOMIC_RELAXED,                    \
                                     __HIP_MEMORY_SCOPE_AGENT) <               \
                   (unsigned)(phase * NBLK))                                   \
                __builtin_amdgcn_s_sleep(8);                                   \
        }                                                                      \
        __syncthreads();                                                       \
        asm volatile("" ::: "memory");                                         \
    } while (0)

// No-shift lse over 16 per-lane log2-domain values: S = sum 2^z (wave-wide),
// u2 = -log2(S); col partials cs[e] += 2^z[e] / S. Safe: |z| << 126.
__device__ __forceinline__ void sum16(const float* z, float* cs, float& u2) {
    float p[16], s = 0.f;
#pragma unroll
    for (int e = 0; e < 16; ++e) {
        p[e] = __builtin_amdgcn_exp2f(z[e]);
        s += p[e];
    }
    s = wave_sum64(s);
    const float rs = __builtin_amdgcn_rcpf(s);
#pragma unroll
    for (int e = 0; e < 16; ++e) cs[e] += p[e] * rs;
    u2 = -__builtin_amdgcn_logf(s);  // v_log_f32 = log2
}

__device__ __forceinline__ void nt_store4(float* p, f4 v) {
    __builtin_nontemporal_store(v, reinterpret_cast<f4*>(p));
}
__device__ __forceinline__ f4 nt_load4(const float* p) {
    return __builtin_nontemporal_load(reinterpret_cast<const f4*>(p));
}

__device__ __forceinline__ unsigned pack_h2(float a, float b) {
    union { h16 h[2]; unsigned u; } r;
    r.h[0] = (h16)a; r.h[1] = (h16)b;
    return r.u;
}
__device__ __forceinline__ void unpack_h2(unsigned u, float& a, float& b) {
    union { unsigned u; h16 h[2]; } r;
    r.u = u;
    a = (float)r.h[0]; b = (float)r.h[1];
}

__global__ __launch_bounds__(256, 4) void sinkhorn_fused(
    const float* __restrict__ m, const int* __restrict__ nrows,
    const int* __restrict__ ncols, unsigned* __restrict__ P16,
    h16* __restrict__ mh, unsigned* __restrict__ bar, float* __restrict__ out,
    int B) {
    const int sub = blockIdx.x % NBLK;  // block within batch
    const int b = blockIdx.x / NBLK;    // batch
    const int w = threadIdx.x >> 6;
    const int lane = threadIdx.x & 63;
    const int wid = sub * 4 + w;  // wave id within batch [0, WPB)
    const int tid = threadIdx.x;
    const int nr = nrows[b];
    const int nc = ncols[b];
    unsigned* ctr = bar + (size_t)b * 16;
    int phase = 0;

    __shared__ float pbuf[4][64][17];  // 17KB padded: conflict-free merge
    __shared__ float vloc[MM];         // 4KB full v (log2), block-local
    __shared__ float uloc[NN];         // 4KB u (log2) for this block's rows
    __shared__ float dbuf[4];          // per-wave max |dv| (convergence)

    const size_t mbo = (size_t)b * NN * MM;
    const f4 z4 = {0.f, 0.f, 0.f, 0.f};

    // ---- degenerate batches: all-zero output, exit (no barrier contact) ----
    if (nr == 0 || nc == 0) {
        for (int row = wid; row < NN; row += WPB) {
            float* orow = out + mbo + (size_t)row * MM + lane * 8;
            nt_store4(orow, z4);
            nt_store4(orow + 4, z4);
            nt_store4(orow + 512, z4);
            nt_store4(orow + 516, z4);
        }
        return;
    }

    // P16: [parity][b][sub][512 u32]  (each u32 = fp16 pair, cols 2pc,2pc+1)
    const size_t Psz = (size_t)B * NBLK * (MM / 2);  // u32 units, one parity
    unsigned* Pw0 = P16 + ((size_t)b * NBLK + sub) * (MM / 2);
    const unsigned* Pr0 = P16 + (size_t)b * NBLK * (MM / 2);

    float cs[16];
#pragma unroll
    for (int e = 0; e < 16; ++e) cs[e] = 0.f;

    // ---- F0: fp32 m (NT) -> fp16 mh2=m*log2e, u1, col partial sums ----
    {
        float mk[16];
#pragma unroll
        for (int e = 0; e < 16; ++e) {
            const int col = lane * 8 + (e >> 3) * 512 + (e & 7);
            mk[e] = (col < nc) ? 0.f : BIGNEG;
        }
        int row = wid;
        f4 A0, A1, A2, A3;
        if (row < nr) {
            const float* rp = m + mbo + (size_t)row * MM + lane * 8;
            A0 = nt_load4(rp);
            A1 = nt_load4(rp + 4);
            A2 = nt_load4(rp + 512);
            A3 = nt_load4(rp + 516);
        }
        while (row < nr) {
            const int nx = row + WPB;
            f4 N0, N1, N2, N3;
            if (nx < nr) {  // prefetch next row while reducing current
                const float* rq = m + mbo + (size_t)nx * MM + lane * 8;
                N0 = nt_load4(rq);
                N1 = nt_load4(rq + 4);
                N2 = nt_load4(rq + 512);
                N3 = nt_load4(rq + 516);
            }
            float zs[16], zr[16];
            *reinterpret_cast<f4*>(&zs[0]) = A0;
            *reinterpret_cast<f4*>(&zs[4]) = A1;
            *reinterpret_cast<f4*>(&zs[8]) = A2;
            *reinterpret_cast<f4*>(&zs[12]) = A3;
#pragma unroll
            for (int e = 0; e < 16; ++e) {
                zs[e] *= LOG2E;          // log2 domain
                zr[e] = zs[e] + mk[e];   // masked copy for the reduce
            }
            h8 hv0, hv1;
#pragma unroll
            for (int e = 0; e < 8; ++e) hv0.h[e] = (h16)zs[e];
#pragma unroll
            for (int e = 0; e < 8; ++e) hv1.h[e] = (h16)zs[8 + e];
            h16* rh = mh + mbo + (size_t)row * MM + lane * 8;
            *reinterpret_cast<h8*>(rh) = hv0;        // cached: reused 10x
            *reinterpret_cast<h8*>(rh + 512) = hv1;
            float u;
            sum16(zr, cs, u);
            if (lane == 0) uloc[row] = u;
            A0 = N0; A1 = N1; A2 = N2; A3 = N3;
            row = nx;
        }
    }

    // ---- early zero-fill of invalid rows (NT; overlaps other batches) ----
    for (int row = nr + wid; row < NN; row += WPB) {
        float* orow = out + mbo + (size_t)row * MM + lane * 8;
        nt_store4(orow, z4);
        nt_store4(orow + 4, z4);
        nt_store4(orow + 512, z4);
        nt_store4(orow + 516, z4);
    }

    for (int t = 1; t <= 10; ++t) {
        // ---- merge 4 waves' cs -> block partial (fp16 pairs) -> P[t&1] ----
#pragma unroll
        for (int e = 0; e < 16; ++e) pbuf[w][lane][e] = cs[e];
        __syncthreads();
        {
            unsigned* Pw = Pw0 + (size_t)(t & 1) * Psz;
#pragma unroll
            for (int q = 0; q < 2; ++q) {
                const int pc = tid + q * 256;  // pair index [0,512)
                float sm[2];
#pragma unroll
                for (int h = 0; h < 2; ++h) {
                    const int col = 2 * pc + h;
                    const int ls = (col >> 3) & 63;
                    const int ei = ((col >> 9) << 3) | (col & 7);
                    sm[h] = pbuf[0][ls][ei] + pbuf[1][ls][ei] +
                            pbuf[2][ls][ei] + pbuf[3][ls][ei];
                }
                st_cohu(Pw + pc, pack_h2(sm[0], sm[1]));
            }
        }

        BATCH_BAR();  // all NBLK blocks' partials at coherence point

        // ---- redundant local finalize: full v (log2), fp16 partials ----
        float dv = 0.f;
        {
            const unsigned* Pr = Pr0 + (size_t)(t & 1) * Psz;
#pragma unroll
            for (int q = 0; q < 2; ++q) {
                const int pc = tid + q * 256;  // coalesced u32 reads
                float CS0 = 0.f, CS1 = 0.f;
#pragma unroll
                for (int s16 = 0; s16 < NBLK; ++s16) {
                    float a, c;
                    unpack_h2(ld_cohu(Pr + s16 * (MM / 2) + pc), a, c);
                    CS0 += a; CS1 += c;
                }
                const int col = 2 * pc;
                const float vp0 = (t == 1) ? 0.f : vloc[col];
                const float vp1 = (t == 1) ? 0.f : vloc[col + 1];
                const float vn0c =
                    fminf(fmaxf(vp0 - __log2f(CS0), BIGNEG), 1e30f);
                const float vn1c =
                    fminf(fmaxf(vp1 - __log2f(CS1), BIGNEG), 1e30f);
                dv = fmaxf(dv, fmaxf(fabsf(vn0c - vp0), fabsf(vn1c - vp1)));
                vloc[col] = vn0c;
                vloc[col + 1] = vn1c;
            }
            dv = wave_max64(dv);
            if (lane == 0) dbuf[w] = dv;
        }
        __syncthreads();  // vloc + dbuf ready for all waves
        const float dmax =
            fmaxf(fmaxf(dbuf[0], dbuf[1]), fmaxf(dbuf[2], dbuf[3]));
        if (t == 10 || dmax < DVTHR) break;  // uniform across batch's blocks

        // ---- row pass: u_{t+1} = -lse2_j(mh2+v_t); col sums for v_{t+1} ----
        float vvm[16];
        {
            float tmp[16];
            *reinterpret_cast<f4*>(&tmp[0]) =
                *reinterpret_cast<const f4*>(&vloc[lane * 8]);
            *reinterpret_cast<f4*>(&tmp[4]) =
                *reinterpret_cast<const f4*>(&vloc[lane * 8 + 4]);
            *reinterpret_cast<f4*>(&tmp[8]) =
                *reinterpret_cast<const f4*>(&vloc[lane * 8 + 512]);
            *reinterpret_cast<f4*>(&tmp[12]) =
                *reinterpret_cast<const f4*>(&vloc[lane * 8 + 516]);
#pragma unroll
            for (int e = 0; e < 16; ++e) {
                const int col = lane * 8 + (e >> 3) * 512 + (e & 7);
                vvm[e] = (col < nc) ? tmp[e] : BIGNEG;
            }
        }
#pragma unroll
        for (int e = 0; e < 16; ++e) cs[e] = 0.f;
        {
            // dual-row + next-pair prefetch: 8 h8 loads in flight per wave
            int row = wid;
            h8 a0, a1, b0, b1;
            if (row < nr) {
                const int r2 = (row + WPB < nr) ? row + WPB : nr - 1;  // clamp
                const h16* p0 = mh + mbo + (size_t)row * MM + lane * 8;
                const h16* p1 = mh + mbo + (size_t)r2 * MM + lane * 8;
                a0 = *reinterpret_cast<const h8*>(p0);
                a1 = *reinterpret_cast<const h8*>(p0 + 512);
                b0 = *reinterpret_cast<const h8*>(p1);
                b1 = *reinterpret_cast<const h8*>(p1 + 512);
            }
            while (row < nr) {
                const int next = row + 2 * WPB;
                h8 na0, na1, nb0, nb1;
                if (next < nr) {
                    const int n2 = (next + WPB < nr) ? next + WPB : nr - 1;
                    const h16* p0 = mh + mbo + (size_t)next * MM + lane * 8;
                    const h16* p1 = mh + mbo + (size_t)n2 * MM + lane * 8;
                    na0 = *reinterpret_cast<const h8*>(p0);
                    na1 = *reinterpret_cast<const h8*>(p0 + 512);
                    nb0 = *reinterpret_cast<const h8*>(p1);
                    nb1 = *reinterpret_cast<const h8*>(p1 + 512);
                }
                float z0[16];
#pragma unroll
                for (int e = 0; e < 8; ++e) {
                    z0[e] = (float)a0.h[e] + vvm[e];
                    z0[8 + e] = (float)a1.h[e] + vvm[8 + e];
                }
                float u0;
                sum16(z0, cs, u0);
                if (lane == 0) uloc[row] = u0;
                if (row + WPB < nr) {  // second row valid (wave-uniform)
                    float z1[16];
#pragma unroll
                    for (int e = 0; e < 8; ++e) {
                        z1[e] = (float)b0.h[e] + vvm[e];
                        z1[8 + e] = (float)b1.h[e] + vvm[8 + e];
                    }
                    float u1;
                    sum16(z1, cs, u1);
                    if (lane == 0) uloc[row + WPB] = u1;
                }
                a0 = na0; a1 = na1; b0 = nb0; b1 = nb1;
                row = next;
            }
        }
    }

    // ---- final: out = 2^(mh2 + u_t + v_t), valid rows (NT, prefetch) ----
    {
        float vvm[16];
        float tmp[16];
        *reinterpret_cast<f4*>(&tmp[0]) =
            *reinterpret_cast<const f4*>(&vloc[lane * 8]);
        *reinterpret_cast<f4*>(&tmp[4]) =
            *reinterpret_cast<const f4*>(&vloc[lane * 8 + 4]);
        *reinterpret_cast<f4*>(&tmp[8]) =
            *reinterpret_cast<const f4*>(&vloc[lane * 8 + 512]);
        *reinterpret_cast<f4*>(&tmp[12]) =
            *reinterpret_cast<const f4*>(&vloc[lane * 8 + 516]);
#pragma unroll
        for (int e = 0; e < 16; ++e) {
            const int col = lane * 8 + (e >> 3) * 512 + (e & 7);
            vvm[e] = (col < nc) ? tmp[e] : BIGNEG;
        }
        int row = wid;
        h8 h0, h1;
        if (row < nr) {
            const h16* rh = mh + mbo + (size_t)row * MM + lane * 8;
            h0 = *reinterpret_cast<const h8*>(rh);
            h1 = *reinterpret_cast<const h8*>(rh + 512);
        }
        while (row < nr) {
            const int nx = row + WPB;
            h8 n0, n1;
            if (nx < nr) {
                const h16* rq = mh + mbo + (size_t)nx * MM + lane * 8;
                n0 = *reinterpret_cast<const h8*>(rq);
                n1 = *reinterpret_cast<const h8*>(rq + 512);
            }
            float* orow = out + mbo + (size_t)row * MM + lane * 8;
            const float ui = uloc[row];
            float r[16];
#pragma unroll
            for (int e = 0; e < 8; ++e) {
                r[e] = __builtin_amdgcn_exp2f((float)h0.h[e] + ui + vvm[e]);
                r[8 + e] =
                    __builtin_amdgcn_exp2f((float)h1.h[e] + ui + vvm[8 + e]);
            }
            nt_store4(orow, *reinterpret_cast<f4*>(&r[0]));
            nt_store4(orow + 4, *reinterpret_cast<f4*>(&r[4]));
            nt_store4(orow + 512, *reinterpret_cast<f4*>(&r[8]));
            nt_store4(orow + 516, *reinterpret_cast<f4*>(&r[12]));
            h0 = n0; h1 = n1;
            row = nx;
        }
    }
}

extern "C" void kernel_launch(void* const* d_in, const int* in_sizes, int n_in,
                              void* d_out, int out_size, void* d_ws,
                              size_t ws_size, hipStream_t stream) {
    const float* m = (const float*)d_in[0];
    const int* nrows = (const int*)d_in[1];
    const int* ncols = (const int*)d_in[2];
    const int B = in_sizes[1];

    char* ws = (char*)d_ws;
    unsigned* bar = (unsigned*)ws;            // 4KB
    unsigned* P16 = (unsigned*)(ws + (1u << 20));  // 2 x B*24*512*4B = 6MB
    h16* mh = (h16*)(ws + (16u << 20));       // 128MB
    float* out = (float*)d_out;

    const int nbar = B * 16;
    zero_bar<<<dim3((nbar + 255) / 256), dim3(256), 0, stream>>>(bar, nbar);

    sinkhorn_fused<<<dim3(B * NBLK), dim3(256), 0, stream>>>(
        m, nrows, ncols, P16, mh, bar, out, B);
}

// Round 15
// 573.335 us; speedup vs baseline: 1.1570x; 1.1570x over previous
//
#include <hip/hip_runtime.h>
#include <math.h>

// Persistent Sinkhorn R15 = exact revert to R12 (best measured: 575us total,
// 260us fused), after R14 refuted the occupancy lever in both directions:
//  - R10/R13: min-waves hints >4 make the compiler under-allocate VGPR
//    (40/48) -> scratch spills (+240MB WRITE) -> void experiments.
//  - R14 (clean, VGPR=64): NBLK=24 / 6 blk/CU REGRESSED 260->352us: LDS
//    granularity kept residency <6 (Occ 35% not 48%) while all per-batch
//    coordination costs scaled with NBLK (finalize all-gather +50%, barrier
//    skew, bank conflicts 4.9M->7.3M, degenerate dual-row ILP).
// NBLK=16 / launch_bounds(256,4) is the measured optimum.
//
// Lever ledger (all tested): bytes (NT + fp16 mh + fp16 P: FETCH 512->414MB,
// time flat), instructions (-30% VALU via log2/no-max-shift: time flat),
// ILP (dual-row+prefetch), iterations (early-exit: never fires, kept as
// free), occupancy (refuted), barriers (20->10: the big win). The fused
// kernel sits at its practical floor: ~0.84GB structural beyond-L2 traffic
// + 10 serialized all-to-all phases at measured fabric latency.
//
// ws: bar@0 (4KB) | P16@1MB (2 x 2MB) | mh@16MB (128MB). ws >= 1GB.

#define BIGNEG (-1e30f)
#define LOG2E 1.44269504f
#define DVTHR 0.001953125f  // 2^-9 log2-units convergence threshold
typedef _Float16 h16;
struct alignas(16) h8 { h16 h[8]; };
typedef float f4 __attribute__((ext_vector_type(4)));  // NT-compatible vec4

#define NN 1024
#define MM 1024
#define NBLK 16  // blocks per batch (4 blocks/CU residency -- optimum)

__device__ __forceinline__ float wave_sum64(float v) {
#pragma unroll
    for (int o = 32; o > 0; o >>= 1) v += __shfl_xor(v, o, 64);
    return v;
}
__device__ __forceinline__ float wave_max64(float v) {
#pragma unroll
    for (int o = 32; o > 0; o >>= 1) v = fmaxf(v, __shfl_xor(v, o, 64));
    return v;
}

__device__ __forceinline__ unsigned ld_cohu(const unsigned* p) {
    return __hip_atomic_load(p, __ATOMIC_RELAXED, __HIP_MEMORY_SCOPE_AGENT);
}
__device__ __forceinline__ void st_cohu(unsigned* p, unsigned v) {
    __hip_atomic_store(p, v, __ATOMIC_RELAXED, __HIP_MEMORY_SCOPE_AGENT);
}

__global__ void zero_bar(unsigned* bar, int n) {
    const int i = blockIdx.x * blockDim.x + threadIdx.x;
    if (i < n) bar[i] = 0;
}

// Monotonic per-batch barrier (proven R3-R12). Relaxed atomics; each wave
// drains its own sc1 stores to the coherence point before arriving.
#define BATCH_BAR()                                                            \
    do {                                                                       \
        asm volatile("s_waitcnt vmcnt(0)" ::: "memory");                       \
        __syncthreads();                                                       \
        ++phase;                                                               \
        if (threadIdx.x == 0) {                                                \
            __hip_atomic_fetch_add(ctr, 1u, __ATOMIC_RELAXED,                  \
                                   __HIP_MEMORY_SCOPE_AGENT);                  \
            while (__hip_atomic_load(ctr, __ATOMIC_RELAXED,                    \
                                     __HIP_MEMORY_SCOPE_AGENT) <               \
                   (unsigned)(phase * NBLK))                                   \
                __builtin_amdgcn_s_sleep(8);                                   \
        }                                                                      \
        __syncthreads();                                                       \
        asm volatile("" ::: "memory");                                         \
    } while (0)

// No-shift lse over 16 per-lane log2-domain values: S = sum 2^z (wave-wide),
// u2 = -log2(S); col partials cs[e] += 2^z[e] / S. Safe: |z| << 126.
__device__ __forceinline__ void sum16(const float* z, float* cs, float& u2) {
    float p[16], s = 0.f;
#pragma unroll
    for (int e = 0; e < 16; ++e) {
        p[e] = __builtin_amdgcn_exp2f(z[e]);
        s += p[e];
    }
    s = wave_sum64(s);
    const float rs = __builtin_amdgcn_rcpf(s);
#pragma unroll
    for (int e = 0; e < 16; ++e) cs[e] += p[e] * rs;
    u2 = -__builtin_amdgcn_logf(s);  // v_log_f32 = log2
}

__device__ __forceinline__ void nt_store4(float* p, f4 v) {
    __builtin_nontemporal_store(v, reinterpret_cast<f4*>(p));
}
__device__ __forceinline__ f4 nt_load4(const float* p) {
    return __builtin_nontemporal_load(reinterpret_cast<const f4*>(p));
}

__device__ __forceinline__ unsigned pack_h2(float a, float b) {
    union { h16 h[2]; unsigned u; } r;
    r.h[0] = (h16)a; r.h[1] = (h16)b;
    return r.u;
}
__device__ __forceinline__ void unpack_h2(unsigned u, float& a, float& b) {
    union { unsigned u; h16 h[2]; } r;
    r.u = u;
    a = (float)r.h[0]; b = (float)r.h[1];
}

__global__ __launch_bounds__(256, 4) void sinkhorn_fused(
    const float* __restrict__ m, const int* __restrict__ nrows,
    const int* __restrict__ ncols, unsigned* __restrict__ P16,
    h16* __restrict__ mh, unsigned* __restrict__ bar, float* __restrict__ out,
    int B) {
    const int sub = blockIdx.x & (NBLK - 1);
    const int b = blockIdx.x >> 4;
    const int w = threadIdx.x >> 6;
    const int lane = threadIdx.x & 63;
    const int wid = sub * 4 + w;  // wave id within batch [0,64)
    const int tid = threadIdx.x;
    const int nr = nrows[b];
    const int nc = ncols[b];
    unsigned* ctr = bar + (size_t)b * 16;
    int phase = 0;

    __shared__ float pbuf[4][64][17];  // 17KB padded: conflict-free merge
    __shared__ float vloc[MM];         // 4KB full v (log2), block-local
    __shared__ float uloc[NN];         // 4KB u (log2) for this block's rows
    __shared__ float dbuf[4];          // per-wave max |dv| (convergence)

    const size_t mbo = (size_t)b * NN * MM;
    const f4 z4 = {0.f, 0.f, 0.f, 0.f};

    // ---- degenerate batches: all-zero output, exit (no barrier contact) ----
    if (nr == 0 || nc == 0) {
        for (int row = wid; row < NN; row += 64) {
            float* orow = out + mbo + (size_t)row * MM + lane * 8;
            nt_store4(orow, z4);
            nt_store4(orow + 4, z4);
            nt_store4(orow + 512, z4);
            nt_store4(orow + 516, z4);
        }
        return;
    }

    // P16: [parity][b][sub][512 u32]  (each u32 = fp16 pair, cols 2pc,2pc+1)
    const size_t Psz = (size_t)B * NBLK * (MM / 2);  // u32 units, one parity
    unsigned* Pw0 = P16 + ((size_t)b * NBLK + sub) * (MM / 2);
    const unsigned* Pr0 = P16 + (size_t)b * NBLK * (MM / 2);

    float cs[16];
#pragma unroll
    for (int e = 0; e < 16; ++e) cs[e] = 0.f;

    // ---- F0: fp32 m (NT) -> fp16 mh2=m*log2e, u1, col partial sums ----
    {
        float mk[16];
#pragma unroll
        for (int e = 0; e < 16; ++e) {
            const int col = lane * 8 + (e >> 3) * 512 + (e & 7);
            mk[e] = (col < nc) ? 0.f : BIGNEG;
        }
        int row = wid;
        f4 A0, A1, A2, A3;
        if (row < nr) {
            const float* rp = m + mbo + (size_t)row * MM + lane * 8;
            A0 = nt_load4(rp);
            A1 = nt_load4(rp + 4);
            A2 = nt_load4(rp + 512);
            A3 = nt_load4(rp + 516);
        }
        while (row < nr) {
            const int nx = row + 64;
            f4 N0, N1, N2, N3;
            if (nx < nr) {  // prefetch next row while reducing current
                const float* rq = m + mbo + (size_t)nx * MM + lane * 8;
                N0 = nt_load4(rq);
                N1 = nt_load4(rq + 4);
                N2 = nt_load4(rq + 512);
                N3 = nt_load4(rq + 516);
            }
            float zs[16], zr[16];
            *reinterpret_cast<f4*>(&zs[0]) = A0;
            *reinterpret_cast<f4*>(&zs[4]) = A1;
            *reinterpret_cast<f4*>(&zs[8]) = A2;
            *reinterpret_cast<f4*>(&zs[12]) = A3;
#pragma unroll
            for (int e = 0; e < 16; ++e) {
                zs[e] *= LOG2E;          // log2 domain
                zr[e] = zs[e] + mk[e];   // masked copy for the reduce
            }
            h8 hv0, hv1;
#pragma unroll
            for (int e = 0; e < 8; ++e) hv0.h[e] = (h16)zs[e];
#pragma unroll
            for (int e = 0; e < 8; ++e) hv1.h[e] = (h16)zs[8 + e];
            h16* rh = mh + mbo + (size_t)row * MM + lane * 8;
            *reinterpret_cast<h8*>(rh) = hv0;        // cached: reused 10x
            *reinterpret_cast<h8*>(rh + 512) = hv1;
            float u;
            sum16(zr, cs, u);
            if (lane == 0) uloc[row] = u;
            A0 = N0; A1 = N1; A2 = N2; A3 = N3;
            row = nx;
        }
    }

    // ---- early zero-fill of invalid rows (NT; overlaps other batches) ----
    for (int row = nr + wid; row < NN; row += 64) {
        float* orow = out + mbo + (size_t)row * MM + lane * 8;
        nt_store4(orow, z4);
        nt_store4(orow + 4, z4);
        nt_store4(orow + 512, z4);
        nt_store4(orow + 516, z4);
    }

    for (int t = 1; t <= 10; ++t) {
        // ---- merge 4 waves' cs -> block partial (fp16 pairs) -> P[t&1] ----
#pragma unroll
        for (int e = 0; e < 16; ++e) pbuf[w][lane][e] = cs[e];
        __syncthreads();
        {
            unsigned* Pw = Pw0 + (size_t)(t & 1) * Psz;
#pragma unroll
            for (int q = 0; q < 2; ++q) {
                const int pc = tid + q * 256;  // pair index [0,512)
                float sm[2];
#pragma unroll
                for (int h = 0; h < 2; ++h) {
                    const int col = 2 * pc + h;
                    const int ls = (col >> 3) & 63;
                    const int ei = ((col >> 9) << 3) | (col & 7);
                    sm[h] = pbuf[0][ls][ei] + pbuf[1][ls][ei] +
                            pbuf[2][ls][ei] + pbuf[3][ls][ei];
                }
                st_cohu(Pw + pc, pack_h2(sm[0], sm[1]));
            }
        }

        BATCH_BAR();  // all 16 blocks' partials at coherence point

        // ---- redundant local finalize: full v (log2), fp16 partials ----
        float dv = 0.f;
        {
            const unsigned* Pr = Pr0 + (size_t)(t & 1) * Psz;
#pragma unroll
            for (int q = 0; q < 2; ++q) {
                const int pc = tid + q * 256;  // coalesced u32 reads
                float CS0 = 0.f, CS1 = 0.f;
#pragma unroll
                for (int s16 = 0; s16 < NBLK; ++s16) {
                    float a, c;
                    unpack_h2(ld_cohu(Pr + s16 * (MM / 2) + pc), a, c);
                    CS0 += a; CS1 += c;
                }
                const int col = 2 * pc;
                const float vp0 = (t == 1) ? 0.f : vloc[col];
                const float vp1 = (t == 1) ? 0.f : vloc[col + 1];
                const float vn0c =
                    fminf(fmaxf(vp0 - __log2f(CS0), BIGNEG), 1e30f);
                const float vn1c =
                    fminf(fmaxf(vp1 - __log2f(CS1), BIGNEG), 1e30f);
                dv = fmaxf(dv, fmaxf(fabsf(vn0c - vp0), fabsf(vn1c - vp1)));
                vloc[col] = vn0c;
                vloc[col + 1] = vn1c;
            }
            dv = wave_max64(dv);
            if (lane == 0) dbuf[w] = dv;
        }
        __syncthreads();  // vloc + dbuf ready for all waves
        const float dmax =
            fmaxf(fmaxf(dbuf[0], dbuf[1]), fmaxf(dbuf[2], dbuf[3]));
        if (t == 10 || dmax < DVTHR) break;  // uniform across batch's blocks

        // ---- row pass: u_{t+1} = -lse2_j(mh2+v_t); col sums for v_{t+1} ----
        float vvm[16];
        {
            float tmp[16];
            *reinterpret_cast<f4*>(&tmp[0]) =
                *reinterpret_cast<const f4*>(&vloc[lane * 8]);
            *reinterpret_cast<f4*>(&tmp[4]) =
                *reinterpret_cast<const f4*>(&vloc[lane * 8 + 4]);
            *reinterpret_cast<f4*>(&tmp[8]) =
                *reinterpret_cast<const f4*>(&vloc[lane * 8 + 512]);
            *reinterpret_cast<f4*>(&tmp[12]) =
                *reinterpret_cast<const f4*>(&vloc[lane * 8 + 516]);
#pragma unroll
            for (int e = 0; e < 16; ++e) {
                const int col = lane * 8 + (e >> 3) * 512 + (e & 7);
                vvm[e] = (col < nc) ? tmp[e] : BIGNEG;
            }
        }
#pragma unroll
        for (int e = 0; e < 16; ++e) cs[e] = 0.f;
        {
            // dual-row + next-pair prefetch: 8 h8 loads in flight per wave
            int row = wid;
            h8 a0, a1, b0, b1;
            if (row < nr) {
                const int r2 = (row + 64 < nr) ? row + 64 : nr - 1;  // clamp
                const h16* p0 = mh + mbo + (size_t)row * MM + lane * 8;
                const h16* p1 = mh + mbo + (size_t)r2 * MM + lane * 8;
                a0 = *reinterpret_cast<const h8*>(p0);
                a1 = *reinterpret_cast<const h8*>(p0 + 512);
                b0 = *reinterpret_cast<const h8*>(p1);
                b1 = *reinterpret_cast<const h8*>(p1 + 512);
            }
            while (row < nr) {
                const int next = row + 128;
                h8 na0, na1, nb0, nb1;
                if (next < nr) {
                    const int n2 = (next + 64 < nr) ? next + 64 : nr - 1;
                    const h16* p0 = mh + mbo + (size_t)next * MM + lane * 8;
                    const h16* p1 = mh + mbo + (size_t)n2 * MM + lane * 8;
                    na0 = *reinterpret_cast<const h8*>(p0);
                    na1 = *reinterpret_cast<const h8*>(p0 + 512);
                    nb0 = *reinterpret_cast<const h8*>(p1);
                    nb1 = *reinterpret_cast<const h8*>(p1 + 512);
                }
                float z0[16];
#pragma unroll
                for (int e = 0; e < 8; ++e) {
                    z0[e] = (float)a0.h[e] + vvm[e];
                    z0[8 + e] = (float)a1.h[e] + vvm[8 + e];
                }
                float u0;
                sum16(z0, cs, u0);
                if (lane == 0) uloc[row] = u0;
                if (row + 64 < nr) {  // second row valid (wave-uniform)
                    float z1[16];
#pragma unroll
                    for (int e = 0; e < 8; ++e) {
                        z1[e] = (float)b0.h[e] + vvm[e];
                        z1[8 + e] = (float)b1.h[e] + vvm[8 + e];
                    }
                    float u1;
                    sum16(z1, cs, u1);
                    if (lane == 0) uloc[row + 64] = u1;
                }
                a0 = na0; a1 = na1; b0 = nb0; b1 = nb1;
                row = next;
            }
        }
    }

    // ---- final: out = 2^(mh2 + u_t + v_t), valid rows (NT, prefetch) ----
    {
        float vvm[16];
        float tmp[16];
        *reinterpret_cast<f4*>(&tmp[0]) =
            *reinterpret_cast<const f4*>(&vloc[lane * 8]);
        *reinterpret_cast<f4*>(&tmp[4]) =
            *reinterpret_cast<const f4*>(&vloc[lane * 8 + 4]);
        *reinterpret_cast<f4*>(&tmp[8]) =
            *reinterpret_cast<const f4*>(&vloc[lane * 8 + 512]);
        *reinterpret_cast<f4*>(&tmp[12]) =
            *reinterpret_cast<const f4*>(&vloc[lane * 8 + 516]);
#pragma unroll
        for (int e = 0; e < 16; ++e) {
            const int col = lane * 8 + (e >> 3) * 512 + (e & 7);
            vvm[e] = (col < nc) ? tmp[e] : BIGNEG;
        }
        int row = wid;
        h8 h0, h1;
        if (row < nr) {
            const h16* rh = mh + mbo + (size_t)row * MM + lane * 8;
            h0 = *reinterpret_cast<const h8*>(rh);
            h1 = *reinterpret_cast<const h8*>(rh + 512);
        }
        while (row < nr) {
            const int nx = row + 64;
            h8 n0, n1;
            if (nx < nr) {
                const h16* rq = mh + mbo + (size_t)nx * MM + lane * 8;
                n0 = *reinterpret_cast<const h8*>(rq);
                n1 = *reinterpret_cast<const h8*>(rq + 512);
            }
            float* orow = out + mbo + (size_t)row * MM + lane * 8;
            const float ui = uloc[row];
            float r[16];
#pragma unroll
            for (int e = 0; e < 8; ++e) {
                r[e] = __builtin_amdgcn_exp2f((float)h0.h[e] + ui + vvm[e]);
                r[8 + e] =
                    __builtin_amdgcn_exp2f((float)h1.h[e] + ui + vvm[8 + e]);
            }
            nt_store4(orow, *reinterpret_cast<f4*>(&r[0]));
            nt_store4(orow + 4, *reinterpret_cast<f4*>(&r[4]));
            nt_store4(orow + 512, *reinterpret_cast<f4*>(&r[8]));
            nt_store4(orow + 516, *reinterpret_cast<f4*>(&r[12]));
            h0 = n0; h1 = n1;
            row = nx;
        }
    }
}

extern "C" void kernel_launch(void* const* d_in, const int* in_sizes, int n_in,
                              void* d_out, int out_size, void* d_ws,
                              size_t ws_size, hipStream_t stream) {
    const float* m = (const float*)d_in[0];
    const int* nrows = (const int*)d_in[1];
    const int* ncols = (const int*)d_in[2];
    const int B = in_sizes[1];

    char* ws = (char*)d_ws;
    unsigned* bar = (unsigned*)ws;            // 4KB
    unsigned* P16 = (unsigned*)(ws + (1u << 20));  // 2 x B*16*512*4B = 4MB
    h16* mh = (h16*)(ws + (16u << 20));       // 128MB
    float* out = (float*)d_out;

    const int nbar = B * 16;
    zero_bar<<<dim3((nbar + 255) / 256), dim3(256), 0, stream>>>(bar, nbar);

    sinkhorn_fused<<<dim3(B * NBLK), dim3(256), 0, stream>>>(
        m, nrows, ncols, P16, mh, bar, out, B);
}